// Round 1
// baseline (3010.540 us; speedup 1.0000x reference)
//
#include <hip/hip_runtime.h>
#include <hip/hip_bf16.h>
#include <math.h>

#define N_NODES 50000
#define N_EDGES 800000
#define IN_DIM  128
#define MEM_DIM 32
#define Z_DIM   160
#define OUT_DIM 64

typedef __attribute__((ext_vector_type(8))) short bf16x8;
typedef __attribute__((ext_vector_type(4))) float f32x4;

__device__ __forceinline__ short f2bf(float f) {
    union { float f; unsigned u; } v; v.f = f;
    unsigned r = v.u + 0x7FFF + ((v.u >> 16) & 1);   // round-to-nearest-even
    return (short)(r >> 16);
}

// ---------------------------------------------------------------------------
// Kernel A: node GEMM  [N,160] @ [160, 4x64] -> zq, zk, zv (ws) and zskip (out)
// block = 256 threads = 4 waves; block covers 16 nodes; wave w handles matrix w.
// ---------------------------------------------------------------------------
__global__ __launch_bounds__(256) void node_gemm(
    const float* __restrict__ x, const float* __restrict__ mem,
    const float* __restrict__ Wq, const float* __restrict__ Wk,
    const float* __restrict__ Wv, const float* __restrict__ Wskip,
    float* __restrict__ zq, float* __restrict__ zk, float* __restrict__ zv,
    float* __restrict__ out)
{
    const int tid  = threadIdx.x;
    const int w    = tid >> 6;
    const int lane = tid & 63;
    const int l15  = lane & 15;
    const int quad = lane >> 4;
    const int nb   = blockIdx.x * 16;

    const float* Wm = (w == 0) ? Wq : (w == 1) ? Wk : (w == 2) ? Wv : Wskip;
    float* outp     = (w == 0) ? zq : (w == 1) ? zk : (w == 2) ? zv : out;

    f32x4 acc[4];
    #pragma unroll
    for (int g = 0; g < 4; ++g) acc[g] = (f32x4)0.0f;

    const int node = nb + l15;
    #pragma unroll
    for (int kb = 0; kb < 5; ++kb) {
        const int k0 = kb * 32 + quad * 8;
        const float* zsrc = (kb < 4)
            ? (x   + (size_t)node * IN_DIM  + kb * 32 + quad * 8)
            : (mem + (size_t)node * MEM_DIM + quad * 8);
        bf16x8 afrag;
        #pragma unroll
        for (int j = 0; j < 8; ++j) afrag[j] = f2bf(zsrc[j]);

        #pragma unroll
        for (int g = 0; g < 4; ++g) {
            bf16x8 bfrag;
            #pragma unroll
            for (int j = 0; j < 8; ++j)
                bfrag[j] = f2bf(Wm[(size_t)(k0 + j) * OUT_DIM + 16 * g + l15]);
            acc[g] = __builtin_amdgcn_mfma_f32_16x16x32_bf16(afrag, bfrag, acc[g], 0, 0, 0);
        }
    }
    // C layout: col = lane&15 (within group), row m = quad*4 + reg
    #pragma unroll
    for (int g = 0; g < 4; ++g) {
        #pragma unroll
        for (int r = 0; r < 4; ++r) {
            const int nrow = nb + quad * 4 + r;
            outp[(size_t)nrow * OUT_DIM + 16 * g + l15] = acc[g][r];
        }
    }
}

// ---------------------------------------------------------------------------
// Kernel B: per-edge. Phase 1: te = cos(t*w+b) -> MFMA te@[We_k|We_v], C->LDS
// (transposed to edge-major). Phase 2: 4 threads/edge gather zq[dst]/zk[src]/
// zv[src] as float4s, score -> exp -> atomic scatter into agg/ssum.
// block = 256 threads = 4 waves; 64 edges per block.
// ---------------------------------------------------------------------------
__global__ __launch_bounds__(256) void edge_kernel(
    const int* __restrict__ src, const int* __restrict__ dst,
    const float* __restrict__ t,
    const float* __restrict__ w_time, const float* __restrict__ b_time,
    const float* __restrict__ We_k, const float* __restrict__ We_v,
    const float* __restrict__ zq, const float* __restrict__ zk,
    const float* __restrict__ zv,
    float* __restrict__ agg, float* __restrict__ ssum)
{
    __shared__ float lds[64 * 132];   // 64 edges x 128 cols, row stride 132 (pad)
    const int tid  = threadIdx.x;
    const int w    = tid >> 6;
    const int lane = tid & 63;
    const int l15  = lane & 15;
    const int quad = lane >> 4;
    const int eb0  = blockIdx.x * 64;

    // per-lane constants: time-encoder params for k = quad*8+j
    float wt[8], bt[8];
    #pragma unroll
    for (int j = 0; j < 8; ++j) {
        wt[j] = w_time[quad * 8 + j];
        bt[j] = b_time[quad * 8 + j];
    }
    // B-frags for [We_k | We_v] held in registers for the whole kernel:
    // B[k = quad*8+j][n = 16*(g&3)+l15], g<4 -> We_k, g>=4 -> We_v
    bf16x8 bfrag[8];
    #pragma unroll
    for (int g = 0; g < 8; ++g) {
        const float* W = (g < 4) ? We_k : We_v;
        const int col = 16 * (g & 3) + l15;
        #pragma unroll
        for (int j = 0; j < 8; ++j)
            bfrag[g][j] = f2bf(W[(quad * 8 + j) * OUT_DIM + col]);
    }

    // ---- phase 1: te + MFMA, write C to LDS (edge-major, padded) ----
    {
        const int e = eb0 + 16 * w + l15;       // A row m = l15
        const float tv = t[e];
        bf16x8 afrag;
        #pragma unroll
        for (int j = 0; j < 8; ++j)
            afrag[j] = f2bf(__cosf(tv * wt[j] + bt[j]));
        #pragma unroll
        for (int g = 0; g < 8; ++g) {
            f32x4 c = __builtin_amdgcn_mfma_f32_16x16x32_bf16(afrag, bfrag[g], (f32x4)0.0f, 0, 0, 0);
            #pragma unroll
            for (int r = 0; r < 4; ++r) {
                const int row = 16 * w + quad * 4 + r;   // edge-in-block
                lds[row * 132 + 16 * g + l15] = c[r];
            }
        }
    }
    __syncthreads();

    // ---- phase 2: 4 threads per edge, thread p owns cols 16p..16p+15 ----
    const int el = tid >> 2;          // edge in block 0..63
    const int p  = tid & 3;           // head = p>>1 (cols 0..31 head0)
    const int e  = eb0 + el;
    const int s  = src[e];
    const int d  = dst[e];

    const float4* qv = (const float4*)(zq + (size_t)d * OUT_DIM + 16 * p);
    const float4* kv = (const float4*)(zk + (size_t)s * OUT_DIM + 16 * p);
    const float4* vv = (const float4*)(zv + (size_t)s * OUT_DIM + 16 * p);
    const float*  lk = lds + el * 132 + 16 * p;        // te@We_k part
    const float*  lv = lds + el * 132 + 64 + 16 * p;   // te@We_v part

    float partial = 0.f;
    float4 vfin[4];
    #pragma unroll
    for (int i = 0; i < 4; ++i) {
        const float4 q  = qv[i];
        const float4 k  = kv[i];
        const float4 v  = vv[i];
        const float4 ek = *(const float4*)(lk + 4 * i);
        const float4 ev = *(const float4*)(lv + 4 * i);
        partial += q.x * (k.x + ek.x) + q.y * (k.y + ek.y)
                 + q.z * (k.z + ek.z) + q.w * (k.w + ek.w);
        vfin[i].x = v.x + ev.x; vfin[i].y = v.y + ev.y;
        vfin[i].z = v.z + ev.z; vfin[i].w = v.w + ev.w;
    }
    // reduce over the head's 2 col-chunks (lanes p and p^1, same wave)
    const float score = (partial + __shfl_xor(partial, 1, 64)) * 0.17677669529663687f;
    const float pe = __expf(score);   // no max-subtract: shift-invariant, |score| small

    if ((p & 1) == 0) atomicAdd(ssum + (size_t)d * 2 + (p >> 1), pe);

    float* aggp = agg + (size_t)d * OUT_DIM + 16 * p;
    #pragma unroll
    for (int i = 0; i < 4; ++i) {
        atomicAdd(aggp + 4 * i + 0, pe * vfin[i].x);
        atomicAdd(aggp + 4 * i + 1, pe * vfin[i].y);
        atomicAdd(aggp + 4 * i + 2, pe * vfin[i].z);
        atomicAdd(aggp + 4 * i + 3, pe * vfin[i].w);
    }
}

// ---------------------------------------------------------------------------
// Kernel C: out = zskip (already in d_out) + agg / ssum
// ---------------------------------------------------------------------------
__global__ __launch_bounds__(256) void finalize_kernel(
    const float* __restrict__ agg, const float* __restrict__ ssum,
    float* __restrict__ out)
{
    const int i = blockIdx.x * 256 + threadIdx.x;
    if (i >= N_NODES * OUT_DIM) return;
    const int n = i >> 6;
    const int h = (i >> 5) & 1;
    const float s = ssum[n * 2 + h];
    const float a = (s > 0.f) ? agg[i] / s : 0.f;
    out[i] += a;
}

extern "C" void kernel_launch(void* const* d_in, const int* in_sizes, int n_in,
                              void* d_out, int out_size, void* d_ws, size_t ws_size,
                              hipStream_t stream) {
    (void)in_sizes; (void)n_in; (void)out_size; (void)ws_size;
    const int*   src    = (const int*)d_in[0];
    const int*   dst    = (const int*)d_in[1];
    const float* t      = (const float*)d_in[2];
    const float* x      = (const float*)d_in[3];
    const float* mem    = (const float*)d_in[4];
    const float* w_time = (const float*)d_in[5];
    const float* b_time = (const float*)d_in[6];
    const float* Wq     = (const float*)d_in[7];
    const float* Wk     = (const float*)d_in[8];
    const float* Wv     = (const float*)d_in[9];
    const float* We_k   = (const float*)d_in[10];
    const float* We_v   = (const float*)d_in[11];
    const float* Wskip  = (const float*)d_in[12];

    float* ws   = (float*)d_ws;
    float* zq   = ws;
    float* zk   = zq + (size_t)N_NODES * OUT_DIM;
    float* zv   = zk + (size_t)N_NODES * OUT_DIM;
    float* agg  = zv + (size_t)N_NODES * OUT_DIM;
    float* ssum = agg + (size_t)N_NODES * OUT_DIM;
    float* out  = (float*)d_out;

    // zero agg + ssum (ws is poisoned 0xAA before every launch)
    hipMemsetAsync(agg, 0, ((size_t)N_NODES * OUT_DIM + (size_t)N_NODES * 2) * sizeof(float), stream);

    node_gemm<<<N_NODES / 16, 256, 0, stream>>>(x, mem, Wq, Wk, Wv, Wskip, zq, zk, zv, out);
    edge_kernel<<<N_EDGES / 64, 256, 0, stream>>>(src, dst, t, w_time, b_time,
                                                  We_k, We_v, zq, zk, zv, agg, ssum);
    finalize_kernel<<<(N_NODES * OUT_DIM) / 256, 256, 0, stream>>>(agg, ssum, out);
}

// Round 2
// 567.141 us; speedup vs baseline: 5.3083x; 5.3083x over previous
//
#include <hip/hip_runtime.h>
#include <hip/hip_bf16.h>
#include <math.h>

#define N_NODES 50000
#define N_EDGES 800000
#define IN_DIM  128
#define MEM_DIM 32
#define Z_DIM   160
#define OUT_DIM 64
#define NB_SCAN ((N_NODES + 255) / 256)   // 196

typedef __attribute__((ext_vector_type(8))) short bf16x8;
typedef __attribute__((ext_vector_type(4))) float f32x4;

__device__ __forceinline__ short f2bf(float f) {
    union { float f; unsigned u; } v; v.f = f;
    unsigned r = v.u + 0x7FFF + ((v.u >> 16) & 1);   // round-to-nearest-even
    return (short)(r >> 16);
}

// ---------------------------------------------------------------------------
// Kernel A: node GEMM  [N,160] @ [160, 4x64] -> zq, zk, zv (ws) and zskip (out)
// ---------------------------------------------------------------------------
__global__ __launch_bounds__(256) void node_gemm(
    const float* __restrict__ x, const float* __restrict__ mem,
    const float* __restrict__ Wq, const float* __restrict__ Wk,
    const float* __restrict__ Wv, const float* __restrict__ Wskip,
    float* __restrict__ zq, float* __restrict__ zk, float* __restrict__ zv,
    float* __restrict__ out)
{
    const int tid  = threadIdx.x;
    const int w    = tid >> 6;
    const int lane = tid & 63;
    const int l15  = lane & 15;
    const int quad = lane >> 4;
    const int nb   = blockIdx.x * 16;

    const float* Wm = (w == 0) ? Wq : (w == 1) ? Wk : (w == 2) ? Wv : Wskip;
    float* outp     = (w == 0) ? zq : (w == 1) ? zk : (w == 2) ? zv : out;

    f32x4 acc[4];
    #pragma unroll
    for (int g = 0; g < 4; ++g) acc[g] = (f32x4)0.0f;

    const int node = nb + l15;
    #pragma unroll
    for (int kb = 0; kb < 5; ++kb) {
        const int k0 = kb * 32 + quad * 8;
        const float* zsrc = (kb < 4)
            ? (x   + (size_t)node * IN_DIM  + kb * 32 + quad * 8)
            : (mem + (size_t)node * MEM_DIM + quad * 8);
        bf16x8 afrag;
        #pragma unroll
        for (int j = 0; j < 8; ++j) afrag[j] = f2bf(zsrc[j]);

        #pragma unroll
        for (int g = 0; g < 4; ++g) {
            bf16x8 bfrag;
            #pragma unroll
            for (int j = 0; j < 8; ++j)
                bfrag[j] = f2bf(Wm[(size_t)(k0 + j) * OUT_DIM + 16 * g + l15]);
            acc[g] = __builtin_amdgcn_mfma_f32_16x16x32_bf16(afrag, bfrag, acc[g], 0, 0, 0);
        }
    }
    #pragma unroll
    for (int g = 0; g < 4; ++g) {
        #pragma unroll
        for (int r = 0; r < 4; ++r) {
            const int nrow = nb + quad * 4 + r;
            outp[(size_t)nrow * OUT_DIM + 16 * g + l15] = acc[g][r];
        }
    }
}

// ---------------------------------------------------------------------------
// Counting sort by dst: hist -> 3-kernel exclusive scan -> scatter
// ---------------------------------------------------------------------------
__global__ __launch_bounds__(256) void hist_k(const int* __restrict__ dst,
                                              int* __restrict__ cnt)
{
    const int e = blockIdx.x * 256 + threadIdx.x;   // E % 256 == 0
    atomicAdd(&cnt[dst[e]], 1);
}

__global__ __launch_bounds__(256) void scan1_k(const int* __restrict__ cnt,
                                               int* __restrict__ base,
                                               int* __restrict__ bsum)
{
    __shared__ int sh[256];
    const int i = blockIdx.x * 256 + threadIdx.x;
    const int v = (i < N_NODES) ? cnt[i] : 0;
    sh[threadIdx.x] = v;
    __syncthreads();
    int val = v;
    for (int off = 1; off < 256; off <<= 1) {
        const int y = (threadIdx.x >= off) ? sh[threadIdx.x - off] : 0;
        __syncthreads();
        val += y; sh[threadIdx.x] = val;
        __syncthreads();
    }
    if (i < N_NODES) base[i] = val - v;            // exclusive
    if (threadIdx.x == 255) bsum[blockIdx.x] = val;
}

__global__ __launch_bounds__(256) void scan2_k(int* __restrict__ bsum)
{
    __shared__ int sh[256];
    const int i = threadIdx.x;
    const int v = (i < NB_SCAN) ? bsum[i] : 0;
    sh[i] = v;
    __syncthreads();
    int val = v;
    for (int off = 1; off < 256; off <<= 1) {
        const int y = (i >= off) ? sh[i - off] : 0;
        __syncthreads();
        val += y; sh[i] = val;
        __syncthreads();
    }
    if (i < NB_SCAN) bsum[i] = val - v;
}

__global__ __launch_bounds__(256) void scan3_k(int* __restrict__ base,
                                               const int* __restrict__ bsum)
{
    const int i = blockIdx.x * 256 + threadIdx.x;
    if (i < N_NODES) base[i] += bsum[blockIdx.x];
}

__global__ __launch_bounds__(256) void scatter_k(
    const int* __restrict__ src, const int* __restrict__ dst,
    const float* __restrict__ t, const int* __restrict__ base,
    int* __restrict__ run, int* __restrict__ srcs, int* __restrict__ dsts,
    float* __restrict__ ts)
{
    const int e = blockIdx.x * 256 + threadIdx.x;   // E % 256 == 0
    const int d = dst[e];
    const int pos = base[d] + atomicAdd(&run[d], 1);
    srcs[pos] = src[e];
    dsts[pos] = d;
    ts[pos]   = t[e];
}

// ---------------------------------------------------------------------------
// Kernel B: per-edge over dst-SORTED positions. Phase 1: te MFMA -> LDS.
// Phase 2: 4 thr/edge gather + score + pe*v -> LDS. Phase 3: run-leader
// segmented reduce in LDS -> ~66 atomics per dst-run instead of per edge.
// ---------------------------------------------------------------------------
__global__ __launch_bounds__(256) void edge_kernel(
    const int* __restrict__ srcs, const int* __restrict__ dsts,
    const float* __restrict__ ts,
    const float* __restrict__ w_time, const float* __restrict__ b_time,
    const float* __restrict__ We_k, const float* __restrict__ We_v,
    const float* __restrict__ zq, const float* __restrict__ zk,
    const float* __restrict__ zv,
    float* __restrict__ agg, float* __restrict__ ssum)
{
    __shared__ float lds[64 * 132];   // phase1: 64x128 stride 132; phase3 reuse: 64x66 stride 68
    __shared__ int sdst[64];
    const int tid  = threadIdx.x;
    const int w    = tid >> 6;
    const int lane = tid & 63;
    const int l15  = lane & 15;
    const int quad = lane >> 4;
    const int eb0  = blockIdx.x * 64;

    // ---- phase 1: te = cos(t*wt+bt), MFMA te@[We_k|We_v] -> LDS ----
    {
        float wt[8], bt[8];
        #pragma unroll
        for (int j = 0; j < 8; ++j) {
            wt[j] = w_time[quad * 8 + j];
            bt[j] = b_time[quad * 8 + j];
        }
        bf16x8 bfrag[8];
        #pragma unroll
        for (int g = 0; g < 8; ++g) {
            const float* W = (g < 4) ? We_k : We_v;
            const int col = 16 * (g & 3) + l15;
            #pragma unroll
            for (int j = 0; j < 8; ++j)
                bfrag[g][j] = f2bf(W[(quad * 8 + j) * OUT_DIM + col]);
        }
        const float tv = ts[eb0 + 16 * w + l15];
        bf16x8 afrag;
        #pragma unroll
        for (int j = 0; j < 8; ++j)
            afrag[j] = f2bf(__cosf(tv * wt[j] + bt[j]));
        #pragma unroll
        for (int g = 0; g < 8; ++g) {
            f32x4 c = __builtin_amdgcn_mfma_f32_16x16x32_bf16(afrag, bfrag[g], (f32x4)0.0f, 0, 0, 0);
            #pragma unroll
            for (int r = 0; r < 4; ++r) {
                const int row = 16 * w + quad * 4 + r;
                lds[row * 132 + 16 * g + l15] = c[r];
            }
        }
    }
    __syncthreads();

    // ---- phase 2: 4 threads/edge; thread p owns 16 dims ----
    const int el = tid >> 2;
    const int p  = tid & 3;
    const int e  = eb0 + el;
    const int s  = srcs[e];
    const int d  = dsts[e];

    const float4* qv = (const float4*)(zq + (size_t)d * OUT_DIM + 16 * p);
    const float4* kv = (const float4*)(zk + (size_t)s * OUT_DIM + 16 * p);
    const float4* vv = (const float4*)(zv + (size_t)s * OUT_DIM + 16 * p);
    const float*  lk = lds + el * 132 + 16 * p;
    const float*  lv = lds + el * 132 + 64 + 16 * p;

    float partial = 0.f;
    float4 vfin[4];
    #pragma unroll
    for (int i = 0; i < 4; ++i) {
        const float4 q  = qv[i];
        const float4 k  = kv[i];
        const float4 v  = vv[i];
        const float4 ek = *(const float4*)(lk + 4 * i);
        const float4 ev = *(const float4*)(lv + 4 * i);
        partial += q.x * (k.x + ek.x) + q.y * (k.y + ek.y)
                 + q.z * (k.z + ek.z) + q.w * (k.w + ek.w);
        vfin[i].x = v.x + ev.x; vfin[i].y = v.y + ev.y;
        vfin[i].z = v.z + ev.z; vfin[i].w = v.w + ev.w;
    }
    const float score = (partial + __shfl_xor(partial, 1, 64)) * 0.17677669529663687f;
    const float pe = __expf(score);   // shift-invariant softmax, |score| small

    __syncthreads();   // done reading phase-1 LDS

    // ---- phase 3: stage pe*v into LDS (stride 68), segmented reduce ----
    {
        float* row = lds + el * 68;
        #pragma unroll
        for (int i = 0; i < 4; ++i) {
            row[16 * p + 4 * i + 0] = pe * vfin[i].x;
            row[16 * p + 4 * i + 1] = pe * vfin[i].y;
            row[16 * p + 4 * i + 2] = pe * vfin[i].z;
            row[16 * p + 4 * i + 3] = pe * vfin[i].w;
        }
        if (p == 0) { row[64] = pe; sdst[el] = d; }
        if (p == 2) { row[65] = pe; }
    }
    __syncthreads();

    const bool leader = (el == 0) || (sdst[el] != sdst[el - 1]);
    if (leader) {
        const int dd = sdst[el];
        float r[16];
        #pragma unroll
        for (int i = 0; i < 16; ++i) r[i] = 0.f;
        float ps = 0.f;
        for (int j = el; j < 64 && sdst[j] == dd; ++j) {
            const float* row = lds + j * 68;
            #pragma unroll
            for (int i = 0; i < 16; ++i) r[i] += row[16 * p + i];
            if (p == 0) ps += row[64];
            if (p == 1) ps += row[65];
        }
        float* aggp = agg + (size_t)dd * OUT_DIM + 16 * p;
        #pragma unroll
        for (int i = 0; i < 16; ++i) atomicAdd(aggp + i, r[i]);
        if (p == 0) atomicAdd(ssum + (size_t)dd * 2 + 0, ps);
        if (p == 1) atomicAdd(ssum + (size_t)dd * 2 + 1, ps);
    }
}

// ---------------------------------------------------------------------------
// Kernel C: out = zskip (already in d_out) + agg / ssum
// ---------------------------------------------------------------------------
__global__ __launch_bounds__(256) void finalize_kernel(
    const float* __restrict__ agg, const float* __restrict__ ssum,
    float* __restrict__ out)
{
    const int i = blockIdx.x * 256 + threadIdx.x;
    if (i >= N_NODES * OUT_DIM) return;
    const int n = i >> 6;
    const int h = (i >> 5) & 1;
    const float s = ssum[n * 2 + h];
    const float a = (s > 0.f) ? agg[i] / s : 0.f;
    out[i] += a;
}

extern "C" void kernel_launch(void* const* d_in, const int* in_sizes, int n_in,
                              void* d_out, int out_size, void* d_ws, size_t ws_size,
                              hipStream_t stream) {
    (void)in_sizes; (void)n_in; (void)out_size; (void)ws_size;
    const int*   src    = (const int*)d_in[0];
    const int*   dst    = (const int*)d_in[1];
    const float* t      = (const float*)d_in[2];
    const float* x      = (const float*)d_in[3];
    const float* mem    = (const float*)d_in[4];
    const float* w_time = (const float*)d_in[5];
    const float* b_time = (const float*)d_in[6];
    const float* Wq     = (const float*)d_in[7];
    const float* Wk     = (const float*)d_in[8];
    const float* Wv     = (const float*)d_in[9];
    const float* We_k   = (const float*)d_in[10];
    const float* We_v   = (const float*)d_in[11];
    const float* Wskip  = (const float*)d_in[12];

    float* ws   = (float*)d_ws;
    float* zq   = ws;                                   // 3.2M
    float* zk   = zq + (size_t)N_NODES * OUT_DIM;       // 3.2M
    float* zv   = zk + (size_t)N_NODES * OUT_DIM;       // 3.2M
    float* agg  = zv + (size_t)N_NODES * OUT_DIM;       // 3.2M  -- zeroed
    float* ssum = agg + (size_t)N_NODES * OUT_DIM;      // 100K  -- zeroed
    int*   cnt  = (int*)(ssum + (size_t)N_NODES * 2);   // 50K   -- zeroed
    int*   run  = cnt + N_NODES;                        // 50K   -- zeroed
    int*   base = run + N_NODES;                        // 50K
    int*   bsum = base + N_NODES;                       // 256
    int*   srcs = bsum + 256;                           // 800K
    int*   dsts = srcs + N_EDGES;                       // 800K
    float* ts   = (float*)(dsts + N_EDGES);             // 800K
    float* out  = (float*)d_out;

    // zero agg, ssum, cnt, run in one contiguous memset
    hipMemsetAsync(agg, 0,
        ((size_t)N_NODES * OUT_DIM + (size_t)N_NODES * 2 + 2 * (size_t)N_NODES) * sizeof(float),
        stream);

    node_gemm<<<N_NODES / 16, 256, 0, stream>>>(x, mem, Wq, Wk, Wv, Wskip, zq, zk, zv, out);

    hist_k   <<<N_EDGES / 256, 256, 0, stream>>>(dst, cnt);
    scan1_k  <<<NB_SCAN, 256, 0, stream>>>(cnt, base, bsum);
    scan2_k  <<<1, 256, 0, stream>>>(bsum);
    scan3_k  <<<NB_SCAN, 256, 0, stream>>>(base, bsum);
    scatter_k<<<N_EDGES / 256, 256, 0, stream>>>(src, dst, t, base, run, srcs, dsts, ts);

    edge_kernel<<<N_EDGES / 64, 256, 0, stream>>>(srcs, dsts, ts, w_time, b_time,
                                                  We_k, We_v, zq, zk, zv, agg, ssum);
    finalize_kernel<<<(N_NODES * OUT_DIM) / 256, 256, 0, stream>>>(agg, ssum, out);
}

// Round 3
// 335.890 us; speedup vs baseline: 8.9629x; 1.6885x over previous
//
#include <hip/hip_runtime.h>
#include <hip/hip_bf16.h>
#include <math.h>

#define N_NODES 50000
#define N_EDGES 800000
#define IN_DIM  128
#define MEM_DIM 32
#define Z_DIM   160
#define OUT_DIM 64
#define NB_SCAN ((N_NODES + 255) / 256)   // 196

typedef __attribute__((ext_vector_type(8))) short bf16x8;
typedef __attribute__((ext_vector_type(4))) float f32x4;

__device__ __forceinline__ short f2bf(float f) {
    union { float f; unsigned u; } v; v.f = f;
    unsigned r = v.u + 0x7FFF + ((v.u >> 16) & 1);   // round-to-nearest-even
    return (short)(r >> 16);
}

// ---------------------------------------------------------------------------
// Kernel A: node GEMM  [N,160] @ [160, 4x64] -> zq, zk, zv (ws) and zskip (out)
// block = 256 = 4 waves; wave w handles matrix w; 16 nodes per block.
// ---------------------------------------------------------------------------
__global__ __launch_bounds__(256) void node_gemm(
    const float* __restrict__ x, const float* __restrict__ mem,
    const float* __restrict__ Wq, const float* __restrict__ Wk,
    const float* __restrict__ Wv, const float* __restrict__ Wskip,
    float* __restrict__ zq, float* __restrict__ zk, float* __restrict__ zv,
    float* __restrict__ out)
{
    const int tid  = threadIdx.x;
    const int w    = tid >> 6;
    const int lane = tid & 63;
    const int l15  = lane & 15;
    const int quad = lane >> 4;
    const int nb   = blockIdx.x * 16;

    const float* Wm = (w == 0) ? Wq : (w == 1) ? Wk : (w == 2) ? Wv : Wskip;
    float* outp     = (w == 0) ? zq : (w == 1) ? zk : (w == 2) ? zv : out;

    f32x4 acc[4];
    #pragma unroll
    for (int g = 0; g < 4; ++g) acc[g] = (f32x4)0.0f;

    const int node = nb + l15;
    #pragma unroll
    for (int kb = 0; kb < 5; ++kb) {
        const int k0 = kb * 32 + quad * 8;
        const float* zsrc = (kb < 4)
            ? (x   + (size_t)node * IN_DIM  + kb * 32 + quad * 8)
            : (mem + (size_t)node * MEM_DIM + quad * 8);
        bf16x8 afrag;
        #pragma unroll
        for (int j = 0; j < 8; ++j) afrag[j] = f2bf(zsrc[j]);

        #pragma unroll
        for (int g = 0; g < 4; ++g) {
            bf16x8 bfrag;
            #pragma unroll
            for (int j = 0; j < 8; ++j)
                bfrag[j] = f2bf(Wm[(size_t)(k0 + j) * OUT_DIM + 16 * g + l15]);
            acc[g] = __builtin_amdgcn_mfma_f32_16x16x32_bf16(afrag, bfrag, acc[g], 0, 0, 0);
        }
    }
    #pragma unroll
    for (int g = 0; g < 4; ++g) {
        #pragma unroll
        for (int r = 0; r < 4; ++r) {
            const int nrow = nb + quad * 4 + r;
            outp[(size_t)nrow * OUT_DIM + 16 * g + l15] = acc[g][r];
        }
    }
}

// ---------------------------------------------------------------------------
// Counting sort by dst: hist -> 3-kernel exclusive scan -> packed scatter
// ---------------------------------------------------------------------------
__global__ __launch_bounds__(256) void hist_k(const int* __restrict__ dst,
                                              int* __restrict__ cnt)
{
    const int e = blockIdx.x * 256 + threadIdx.x;   // E % 256 == 0
    atomicAdd(&cnt[dst[e]], 1);
}

__global__ __launch_bounds__(256) void scan1_k(const int* __restrict__ cnt,
                                               int* __restrict__ base,
                                               int* __restrict__ bsum)
{
    __shared__ int sh[256];
    const int i = blockIdx.x * 256 + threadIdx.x;
    const int v = (i < N_NODES) ? cnt[i] : 0;
    sh[threadIdx.x] = v;
    __syncthreads();
    int val = v;
    for (int off = 1; off < 256; off <<= 1) {
        const int y = (threadIdx.x >= off) ? sh[threadIdx.x - off] : 0;
        __syncthreads();
        val += y; sh[threadIdx.x] = val;
        __syncthreads();
    }
    if (i < N_NODES) base[i] = val - v;            // exclusive
    if (threadIdx.x == 255) bsum[blockIdx.x] = val;
}

__global__ __launch_bounds__(256) void scan2_k(int* __restrict__ bsum)
{
    __shared__ int sh[256];
    const int i = threadIdx.x;
    const int v = (i < NB_SCAN) ? bsum[i] : 0;
    sh[i] = v;
    __syncthreads();
    int val = v;
    for (int off = 1; off < 256; off <<= 1) {
        const int y = (i >= off) ? sh[i - off] : 0;
        __syncthreads();
        val += y; sh[i] = val;
        __syncthreads();
    }
    if (i < NB_SCAN) bsum[i] = val - v;
}

__global__ __launch_bounds__(256) void scan3_k(int* __restrict__ base,
                                               const int* __restrict__ bsum)
{
    const int i = blockIdx.x * 256 + threadIdx.x;
    if (i < N_NODES) base[i] += bsum[blockIdx.x];
}

__global__ __launch_bounds__(256) void scatter_k(
    const int* __restrict__ src, const int* __restrict__ dst,
    const float* __restrict__ t, const int* __restrict__ base,
    int* __restrict__ run, int2* __restrict__ edata)
{
    const int e = blockIdx.x * 256 + threadIdx.x;   // E % 256 == 0
    const int d = dst[e];
    const int pos = base[d] + atomicAdd(&run[d], 1);
    edata[pos] = make_int2(src[e], __float_as_int(t[e]));
}

// ---------------------------------------------------------------------------
// Kernel B: gather-style fused attention. One wave per 4 nodes; a node's
// sorted edges are consumed in chunks of 16 (one MFMA A-frag = 16 te rows).
// C layout (col=l15, row=quad*4+r) keeps everything in registers: each quad
// handles 4 edges, 16 lanes span a 16-col chunk. Zero atomics, zero LDS.
// out[n] = skip (already in d_out) + softmax-weighted sum. Replaces
// edge_kernel + finalize_kernel + agg/ssum arrays.
// ---------------------------------------------------------------------------
__global__ __launch_bounds__(256) void gather_edge(
    const int2* __restrict__ edata, const int* __restrict__ base,
    const int* __restrict__ cnt,
    const float* __restrict__ w_time, const float* __restrict__ b_time,
    const float* __restrict__ We_k, const float* __restrict__ We_v,
    const float* __restrict__ zq, const float* __restrict__ zk,
    const float* __restrict__ zv, float* __restrict__ out)
{
    const int tid  = threadIdx.x;
    const int w    = tid >> 6;
    const int lane = tid & 63;
    const int l15  = lane & 15;
    const int quad = lane >> 4;
    const int wid  = blockIdx.x * 4 + w;      // wave id; nodes [wid*4, wid*4+4)

    // per-wave constants (amortized over 4 nodes)
    float wt[8], bt[8];
    #pragma unroll
    for (int j = 0; j < 8; ++j) {
        wt[j] = w_time[quad * 8 + j];
        bt[j] = b_time[quad * 8 + j];
    }
    bf16x8 bfrag[8];   // [We_k | We_v], B[k=quad*8+j][col=16*(g&3)+l15]
    #pragma unroll
    for (int g = 0; g < 8; ++g) {
        const float* W = (g < 4) ? We_k : We_v;
        const int col = 16 * (g & 3) + l15;
        #pragma unroll
        for (int j = 0; j < 8; ++j)
            bfrag[g][j] = f2bf(W[(quad * 8 + j) * OUT_DIM + col]);
    }

    for (int a = 0; a < 4; ++a) {
        const int n   = wid * 4 + a;
        const int b0  = base[n];
        const int deg = cnt[n];

        float q[4];
        #pragma unroll
        for (int g = 0; g < 4; ++g) q[g] = zq[(size_t)n * OUT_DIM + 16 * g + l15];

        float acc0 = 0.f, acc1 = 0.f, acc2 = 0.f, acc3 = 0.f;
        float lp0 = 0.f, lp1 = 0.f;

        for (int ch = 0; ch < deg; ch += 16) {
            const int e_l = b0 + ch + l15;
            const int2 ed = edata[min(e_l, N_EDGES - 1)];
            const float tv = __int_as_float(ed.y);
            bf16x8 afrag;                       // te rows: A[m=l15][k=quad*8+j]
            #pragma unroll
            for (int j = 0; j < 8; ++j)
                afrag[j] = f2bf(__cosf(tv * wt[j] + bt[j]));
            f32x4 c[8];
            #pragma unroll
            for (int g = 0; g < 8; ++g)
                c[g] = __builtin_amdgcn_mfma_f32_16x16x32_bf16(afrag, bfrag[g], (f32x4)0.0f, 0, 0, 0);

            const int rem = deg - ch;           // valid edges in this chunk
            #pragma unroll
            for (int r = 0; r < 4; ++r) {
                const int er   = quad * 4 + r;  // edge-in-chunk (C row)
                const int srcn = __shfl(ed.x, er, 64);
                const bool valid = (er < rem);
                const float* zkrow = zk + (size_t)srcn * OUT_DIM;
                const float* zvrow = zv + (size_t)srcn * OUT_DIM;

                float sc0 = q[0] * (zkrow[l15]      + c[0][r])
                          + q[1] * (zkrow[16 + l15] + c[1][r]);
                float sc1 = q[2] * (zkrow[32 + l15] + c[2][r])
                          + q[3] * (zkrow[48 + l15] + c[3][r]);
                #pragma unroll
                for (int off = 1; off < 16; off <<= 1) {
                    sc0 += __shfl_xor(sc0, off, 64);
                    sc1 += __shfl_xor(sc1, off, 64);
                }
                const float pe0 = valid ? __expf(sc0 * 0.17677669529663687f) : 0.f;
                const float pe1 = valid ? __expf(sc1 * 0.17677669529663687f) : 0.f;
                lp0 += pe0;
                lp1 += pe1;
                acc0 += pe0 * (zvrow[l15]      + c[4][r]);
                acc1 += pe0 * (zvrow[16 + l15] + c[5][r]);
                acc2 += pe1 * (zvrow[32 + l15] + c[6][r]);
                acc3 += pe1 * (zvrow[48 + l15] + c[7][r]);
            }
        }

        // cross-quad reduction (each quad summed only its own edges)
        #pragma unroll
        for (int off = 16; off < 64; off <<= 1) {
            acc0 += __shfl_xor(acc0, off, 64);
            acc1 += __shfl_xor(acc1, off, 64);
            acc2 += __shfl_xor(acc2, off, 64);
            acc3 += __shfl_xor(acc3, off, 64);
            lp0  += __shfl_xor(lp0,  off, 64);
            lp1  += __shfl_xor(lp1,  off, 64);
        }
        // lane writes col = lane: col = 16*quad + l15 -> pick acc[quad]
        const float va = (quad == 0) ? acc0 : (quad == 1) ? acc1
                        : (quad == 2) ? acc2 : acc3;
        const float ls = (quad < 2) ? lp0 : lp1;
        const float res = (ls > 0.f) ? va / ls : 0.f;
        out[(size_t)n * OUT_DIM + lane] += res;   // skip term already there
    }
}

extern "C" void kernel_launch(void* const* d_in, const int* in_sizes, int n_in,
                              void* d_out, int out_size, void* d_ws, size_t ws_size,
                              hipStream_t stream) {
    (void)in_sizes; (void)n_in; (void)out_size; (void)ws_size;
    const int*   src    = (const int*)d_in[0];
    const int*   dst    = (const int*)d_in[1];
    const float* t      = (const float*)d_in[2];
    const float* x      = (const float*)d_in[3];
    const float* mem    = (const float*)d_in[4];
    const float* w_time = (const float*)d_in[5];
    const float* b_time = (const float*)d_in[6];
    const float* Wq     = (const float*)d_in[7];
    const float* Wk     = (const float*)d_in[8];
    const float* Wv     = (const float*)d_in[9];
    const float* We_k   = (const float*)d_in[10];
    const float* We_v   = (const float*)d_in[11];
    const float* Wskip  = (const float*)d_in[12];

    float* ws   = (float*)d_ws;
    float* zq   = ws;                                   // N*64
    float* zk   = zq + (size_t)N_NODES * OUT_DIM;       // N*64
    float* zv   = zk + (size_t)N_NODES * OUT_DIM;       // N*64
    int*   cnt  = (int*)(zv + (size_t)N_NODES * OUT_DIM); // N  -- zeroed
    int*   run  = cnt + N_NODES;                        // N   -- zeroed
    int*   base = run + N_NODES;                        // N
    int*   bsum = base + N_NODES;                       // 256
    int2*  edata = (int2*)(bsum + 256);                 // E int2 (8B aligned: offset even)
    float* out  = (float*)d_out;

    // zero cnt + run (ws is poisoned 0xAA before every launch)
    hipMemsetAsync(cnt, 0, 2 * (size_t)N_NODES * sizeof(int), stream);

    node_gemm<<<N_NODES / 16, 256, 0, stream>>>(x, mem, Wq, Wk, Wv, Wskip, zq, zk, zv, out);

    hist_k   <<<N_EDGES / 256, 256, 0, stream>>>(dst, cnt);
    scan1_k  <<<NB_SCAN, 256, 0, stream>>>(cnt, base, bsum);
    scan2_k  <<<1, 256, 0, stream>>>(bsum);
    scan3_k  <<<NB_SCAN, 256, 0, stream>>>(base, bsum);
    scatter_k<<<N_EDGES / 256, 256, 0, stream>>>(src, dst, t, base, run, edata);

    // 4 nodes per wave, 4 waves per block -> 16 nodes/block, 3125 blocks
    gather_edge<<<N_NODES / 16, 256, 0, stream>>>(edata, base, cnt, w_time, b_time,
                                                  We_k, We_v, zq, zk, zv, out);
}

// Round 4
// 293.499 us; speedup vs baseline: 10.2574x; 1.1444x over previous
//
#include <hip/hip_runtime.h>
#include <hip/hip_bf16.h>
#include <math.h>

#define N_NODES 50000
#define N_EDGES 800000
#define IN_DIM  128
#define MEM_DIM 32
#define Z_DIM   160
#define OUT_DIM 64
#define NB_SCAN ((N_NODES + 255) / 256)   // 196

typedef __attribute__((ext_vector_type(8))) short bf16x8;
typedef __attribute__((ext_vector_type(4))) float f32x4;

__device__ __forceinline__ short f2bf(float f) {
    union { float f; unsigned u; } v; v.f = f;
    unsigned r = v.u + 0x7FFF + ((v.u >> 16) & 1);   // round-to-nearest-even
    return (short)(r >> 16);
}
__device__ __forceinline__ float bf2f(unsigned short u) {
    return __uint_as_float((unsigned)u << 16);
}

// ---------------------------------------------------------------------------
// Kernel A: node GEMM [N,160]@[160,4x64] -> zq (f32), zkv (bf16 k||v), out
// (skip, f32). Also FUSED: per-edge dst histogram + rank capture (grid is
// exactly 800K threads), hidden under the MFMA work.
// ---------------------------------------------------------------------------
__global__ __launch_bounds__(256) void node_gemm(
    const float* __restrict__ x, const float* __restrict__ mem,
    const float* __restrict__ Wq, const float* __restrict__ Wk,
    const float* __restrict__ Wv, const float* __restrict__ Wskip,
    const int* __restrict__ dstE, int* __restrict__ cnt, int* __restrict__ rank,
    float* __restrict__ zq, unsigned short* __restrict__ zkv,
    float* __restrict__ out)
{
    const int tid  = threadIdx.x;
    // fused histogram: one edge per thread (3125 blocks * 256 = 800000 = E)
    {
        const int e = blockIdx.x * 256 + tid;
        rank[e] = atomicAdd(&cnt[dstE[e]], 1);
    }

    const int w    = tid >> 6;
    const int lane = tid & 63;
    const int l15  = lane & 15;
    const int quad = lane >> 4;
    const int nb   = blockIdx.x * 16;

    const float* Wm = (w == 0) ? Wq : (w == 1) ? Wk : (w == 2) ? Wv : Wskip;

    f32x4 acc[4];
    #pragma unroll
    for (int g = 0; g < 4; ++g) acc[g] = (f32x4)0.0f;

    const int node = nb + l15;
    #pragma unroll
    for (int kb = 0; kb < 5; ++kb) {
        const int k0 = kb * 32 + quad * 8;
        const float* zsrc = (kb < 4)
            ? (x   + (size_t)node * IN_DIM  + kb * 32 + quad * 8)
            : (mem + (size_t)node * MEM_DIM + quad * 8);
        bf16x8 afrag;
        #pragma unroll
        for (int j = 0; j < 8; ++j) afrag[j] = f2bf(zsrc[j]);

        #pragma unroll
        for (int g = 0; g < 4; ++g) {
            bf16x8 bfrag;
            #pragma unroll
            for (int j = 0; j < 8; ++j)
                bfrag[j] = f2bf(Wm[(size_t)(k0 + j) * OUT_DIM + 16 * g + l15]);
            acc[g] = __builtin_amdgcn_mfma_f32_16x16x32_bf16(afrag, bfrag, acc[g], 0, 0, 0);
        }
    }
    #pragma unroll
    for (int g = 0; g < 4; ++g) {
        #pragma unroll
        for (int r = 0; r < 4; ++r) {
            const int nrow = nb + quad * 4 + r;
            const int col  = 16 * g + l15;
            if (w == 0)
                zq[(size_t)nrow * OUT_DIM + col] = acc[g][r];
            else if (w == 3)
                out[(size_t)nrow * OUT_DIM + col] = acc[g][r];
            else   // w==1 -> k half, w==2 -> v half; interleaved bf16
                zkv[(size_t)nrow * 128 + (w == 2 ? 64 : 0) + col] =
                    (unsigned short)f2bf(acc[g][r]);
        }
    }
}

// ---------------------------------------------------------------------------
// Scans: per-256-block exclusive scan (scan1), then scan of the 196 block
// sums (scan2). Consumers add bsum[d>>8] themselves (no scan3 pass).
// ---------------------------------------------------------------------------
__global__ __launch_bounds__(256) void scan1_k(const int* __restrict__ cnt,
                                               int* __restrict__ base,
                                               int* __restrict__ bsum)
{
    __shared__ int sh[256];
    const int i = blockIdx.x * 256 + threadIdx.x;
    const int v = (i < N_NODES) ? cnt[i] : 0;
    sh[threadIdx.x] = v;
    __syncthreads();
    int val = v;
    for (int off = 1; off < 256; off <<= 1) {
        const int y = (threadIdx.x >= off) ? sh[threadIdx.x - off] : 0;
        __syncthreads();
        val += y; sh[threadIdx.x] = val;
        __syncthreads();
    }
    if (i < N_NODES) base[i] = val - v;            // exclusive within block
    if (threadIdx.x == 255) bsum[blockIdx.x] = val;
}

__global__ __launch_bounds__(256) void scan2_k(int* __restrict__ bsum)
{
    __shared__ int sh[256];
    const int i = threadIdx.x;
    const int v = (i < NB_SCAN) ? bsum[i] : 0;
    sh[i] = v;
    __syncthreads();
    int val = v;
    for (int off = 1; off < 256; off <<= 1) {
        const int y = (i >= off) ? sh[i - off] : 0;
        __syncthreads();
        val += y; sh[i] = val;
        __syncthreads();
    }
    if (i < NB_SCAN) bsum[i] = val - v;            // exclusive block offsets
}

// ---------------------------------------------------------------------------
// Atomic-free scatter: pos = base[d] + bsum[d>>8] + rank[e]
// ---------------------------------------------------------------------------
__global__ __launch_bounds__(256) void scatter_k(
    const int* __restrict__ src, const int* __restrict__ dst,
    const float* __restrict__ t, const int* __restrict__ base,
    const int* __restrict__ bsum, const int* __restrict__ rank,
    int2* __restrict__ edata)
{
    const int e = blockIdx.x * 256 + threadIdx.x;   // E % 256 == 0
    const int d = dst[e];
    const int pos = base[d] + bsum[d >> 8] + rank[e];
    edata[pos] = make_int2(src[e], __float_as_int(t[e]));
}

// ---------------------------------------------------------------------------
// Kernel B: gather-style fused attention, one wave per 4 nodes. Sorted edges
// consumed in chunks of 16 (one MFMA A-frag of te rows); each quad handles
// 4 edges in parallel. k/v gathered as bf16 from interleaved zkv (256 B/node).
// Zero atomics, zero LDS.
// ---------------------------------------------------------------------------
__global__ __launch_bounds__(256) void gather_edge(
    const int2* __restrict__ edata, const int* __restrict__ base,
    const int* __restrict__ bsum, const int* __restrict__ cnt,
    const float* __restrict__ w_time, const float* __restrict__ b_time,
    const float* __restrict__ We_k, const float* __restrict__ We_v,
    const float* __restrict__ zq, const unsigned short* __restrict__ zkv,
    float* __restrict__ out)
{
    const int tid  = threadIdx.x;
    const int w    = tid >> 6;
    const int lane = tid & 63;
    const int l15  = lane & 15;
    const int quad = lane >> 4;
    const int wid  = blockIdx.x * 4 + w;      // nodes [wid*4, wid*4+4)

    float wt[8], bt[8];
    #pragma unroll
    for (int j = 0; j < 8; ++j) {
        wt[j] = w_time[quad * 8 + j];
        bt[j] = b_time[quad * 8 + j];
    }
    bf16x8 bfrag[8];   // [We_k | We_v], B[k=quad*8+j][col=16*(g&3)+l15]
    #pragma unroll
    for (int g = 0; g < 8; ++g) {
        const float* W = (g < 4) ? We_k : We_v;
        const int col = 16 * (g & 3) + l15;
        #pragma unroll
        for (int j = 0; j < 8; ++j)
            bfrag[g][j] = f2bf(W[(quad * 8 + j) * OUT_DIM + col]);
    }

    for (int a = 0; a < 4; ++a) {
        const int n   = wid * 4 + a;
        const int b0  = base[n] + bsum[n >> 8];
        const int deg = cnt[n];

        float q[4];
        #pragma unroll
        for (int g = 0; g < 4; ++g) q[g] = zq[(size_t)n * OUT_DIM + 16 * g + l15];

        float acc0 = 0.f, acc1 = 0.f, acc2 = 0.f, acc3 = 0.f;
        float lp0 = 0.f, lp1 = 0.f;

        for (int ch = 0; ch < deg; ch += 16) {
            const int e_l = b0 + ch + l15;
            const int2 ed = edata[min(e_l, N_EDGES - 1)];
            const float tv = __int_as_float(ed.y);
            bf16x8 afrag;                       // te rows: A[m=l15][k=quad*8+j]
            #pragma unroll
            for (int j = 0; j < 8; ++j)
                afrag[j] = f2bf(__cosf(tv * wt[j] + bt[j]));
            f32x4 c[8];
            #pragma unroll
            for (int g = 0; g < 8; ++g)
                c[g] = __builtin_amdgcn_mfma_f32_16x16x32_bf16(afrag, bfrag[g], (f32x4)0.0f, 0, 0, 0);

            const int rem = deg - ch;
            #pragma unroll
            for (int r = 0; r < 4; ++r) {
                const int er   = quad * 4 + r;  // edge-in-chunk (C row)
                const int srcn = __shfl(ed.x, er, 64);
                const bool valid = (er < rem);
                const unsigned short* kv = zkv + (size_t)srcn * 128;

                float sc0 = q[0] * (bf2f(kv[l15])      + c[0][r])
                          + q[1] * (bf2f(kv[16 + l15]) + c[1][r]);
                float sc1 = q[2] * (bf2f(kv[32 + l15]) + c[2][r])
                          + q[3] * (bf2f(kv[48 + l15]) + c[3][r]);
                #pragma unroll
                for (int off = 1; off < 16; off <<= 1) {
                    sc0 += __shfl_xor(sc0, off, 64);
                    sc1 += __shfl_xor(sc1, off, 64);
                }
                const float pe0 = valid ? __expf(sc0 * 0.17677669529663687f) : 0.f;
                const float pe1 = valid ? __expf(sc1 * 0.17677669529663687f) : 0.f;
                lp0 += pe0;
                lp1 += pe1;
                acc0 += pe0 * (bf2f(kv[64 + l15])       + c[4][r]);
                acc1 += pe0 * (bf2f(kv[80 + l15])       + c[5][r]);
                acc2 += pe1 * (bf2f(kv[96 + l15])       + c[6][r]);
                acc3 += pe1 * (bf2f(kv[112 + l15])      + c[7][r]);
            }
        }

        #pragma unroll
        for (int off = 16; off < 64; off <<= 1) {
            acc0 += __shfl_xor(acc0, off, 64);
            acc1 += __shfl_xor(acc1, off, 64);
            acc2 += __shfl_xor(acc2, off, 64);
            acc3 += __shfl_xor(acc3, off, 64);
            lp0  += __shfl_xor(lp0,  off, 64);
            lp1  += __shfl_xor(lp1,  off, 64);
        }
        const float va = (quad == 0) ? acc0 : (quad == 1) ? acc1
                        : (quad == 2) ? acc2 : acc3;
        const float ls = (quad < 2) ? lp0 : lp1;
        const float res = (ls > 0.f) ? va / ls : 0.f;
        out[(size_t)n * OUT_DIM + lane] += res;   // skip term already there
    }
}

extern "C" void kernel_launch(void* const* d_in, const int* in_sizes, int n_in,
                              void* d_out, int out_size, void* d_ws, size_t ws_size,
                              hipStream_t stream) {
    (void)in_sizes; (void)n_in; (void)out_size; (void)ws_size;
    const int*   src    = (const int*)d_in[0];
    const int*   dst    = (const int*)d_in[1];
    const float* t      = (const float*)d_in[2];
    const float* x      = (const float*)d_in[3];
    const float* mem    = (const float*)d_in[4];
    const float* w_time = (const float*)d_in[5];
    const float* b_time = (const float*)d_in[6];
    const float* Wq     = (const float*)d_in[7];
    const float* Wk     = (const float*)d_in[8];
    const float* Wv     = (const float*)d_in[9];
    const float* We_k   = (const float*)d_in[10];
    const float* We_v   = (const float*)d_in[11];
    const float* Wskip  = (const float*)d_in[12];

    float*          ws   = (float*)d_ws;
    float*          zq   = ws;                                        // N*64 f32
    unsigned short* zkv  = (unsigned short*)(zq + (size_t)N_NODES * OUT_DIM); // N*128 bf16
    int* cnt  = (int*)(zkv + (size_t)N_NODES * 128);  // N  -- zeroed
    int* rank = cnt + N_NODES;                        // E
    int* base = rank + N_EDGES;                       // N
    int* bsum = base + N_NODES;                       // 256
    int2* edata = (int2*)(bsum + 256);                // E int2 (8B-aligned)
    float* out  = (float*)d_out;

    hipMemsetAsync(cnt, 0, (size_t)N_NODES * sizeof(int), stream);

    node_gemm<<<N_NODES / 16, 256, 0, stream>>>(x, mem, Wq, Wk, Wv, Wskip,
                                                dst, cnt, rank, zq, zkv, out);
    scan1_k  <<<NB_SCAN, 256, 0, stream>>>(cnt, base, bsum);
    scan2_k  <<<1, 256, 0, stream>>>(bsum);
    scatter_k<<<N_EDGES / 256, 256, 0, stream>>>(src, dst, t, base, bsum, rank, edata);
    gather_edge<<<N_NODES / 16, 256, 0, stream>>>(edata, base, bsum, cnt, w_time, b_time,
                                                  We_k, We_v, zq, zkv, out);
}

// Round 5
// 292.664 us; speedup vs baseline: 10.2867x; 1.0029x over previous
//
#include <hip/hip_runtime.h>
#include <hip/hip_bf16.h>
#include <math.h>

#define N_NODES 50000
#define N_EDGES 800000
#define IN_DIM  128
#define MEM_DIM 32
#define Z_DIM   160
#define OUT_DIM 64
#define NB_SCAN ((N_NODES + 255) / 256)   // 196
#define LSTR    132                       // LDS row stride (words); 528 B, 16B-aligned

typedef __attribute__((ext_vector_type(8))) short bf16x8;
typedef __attribute__((ext_vector_type(8))) unsigned short u16x8;
typedef __attribute__((ext_vector_type(4))) float f32x4;

__device__ __forceinline__ short f2bf(float f) {
    union { float f; unsigned u; } v; v.f = f;
    unsigned r = v.u + 0x7FFF + ((v.u >> 16) & 1);   // round-to-nearest-even
    return (short)(r >> 16);
}
__device__ __forceinline__ float bf2f(unsigned short u) {
    return __uint_as_float((unsigned)u << 16);
}

// ---------------------------------------------------------------------------
// Kernel A: node GEMM [N,160]@[160,4x64] -> zq (f32), zkv (bf16 k||v), out
// (skip, f32). FUSED: per-edge dst histogram + rank capture (grid == E threads).
// ---------------------------------------------------------------------------
__global__ __launch_bounds__(256) void node_gemm(
    const float* __restrict__ x, const float* __restrict__ mem,
    const float* __restrict__ Wq, const float* __restrict__ Wk,
    const float* __restrict__ Wv, const float* __restrict__ Wskip,
    const int* __restrict__ dstE, int* __restrict__ cnt, int* __restrict__ rank,
    float* __restrict__ zq, unsigned short* __restrict__ zkv,
    float* __restrict__ out)
{
    const int tid  = threadIdx.x;
    {
        const int e = blockIdx.x * 256 + tid;   // 3125*256 == E
        rank[e] = atomicAdd(&cnt[dstE[e]], 1);
    }

    const int w    = tid >> 6;
    const int lane = tid & 63;
    const int l15  = lane & 15;
    const int quad = lane >> 4;
    const int nb   = blockIdx.x * 16;

    const float* Wm = (w == 0) ? Wq : (w == 1) ? Wk : (w == 2) ? Wv : Wskip;

    f32x4 acc[4];
    #pragma unroll
    for (int g = 0; g < 4; ++g) acc[g] = (f32x4)0.0f;

    const int node = nb + l15;
    #pragma unroll
    for (int kb = 0; kb < 5; ++kb) {
        const int k0 = kb * 32 + quad * 8;
        const float* zsrc = (kb < 4)
            ? (x   + (size_t)node * IN_DIM  + kb * 32 + quad * 8)
            : (mem + (size_t)node * MEM_DIM + quad * 8);
        bf16x8 afrag;
        #pragma unroll
        for (int j = 0; j < 8; ++j) afrag[j] = f2bf(zsrc[j]);

        #pragma unroll
        for (int g = 0; g < 4; ++g) {
            bf16x8 bfrag;
            #pragma unroll
            for (int j = 0; j < 8; ++j)
                bfrag[j] = f2bf(Wm[(size_t)(k0 + j) * OUT_DIM + 16 * g + l15]);
            acc[g] = __builtin_amdgcn_mfma_f32_16x16x32_bf16(afrag, bfrag, acc[g], 0, 0, 0);
        }
    }
    #pragma unroll
    for (int g = 0; g < 4; ++g) {
        #pragma unroll
        for (int r = 0; r < 4; ++r) {
            const int nrow = nb + quad * 4 + r;
            const int col  = 16 * g + l15;
            if (w == 0)
                zq[(size_t)nrow * OUT_DIM + col] = acc[g][r];
            else if (w == 3)
                out[(size_t)nrow * OUT_DIM + col] = acc[g][r];
            else
                zkv[(size_t)nrow * 128 + (w == 2 ? 64 : 0) + col] =
                    (unsigned short)f2bf(acc[g][r]);
        }
    }
}

// ---------------------------------------------------------------------------
// Scans (2-level; consumers add bsum[d>>8] themselves)
// ---------------------------------------------------------------------------
__global__ __launch_bounds__(256) void scan1_k(const int* __restrict__ cnt,
                                               int* __restrict__ base,
                                               int* __restrict__ bsum)
{
    __shared__ int sh[256];
    const int i = blockIdx.x * 256 + threadIdx.x;
    const int v = (i < N_NODES) ? cnt[i] : 0;
    sh[threadIdx.x] = v;
    __syncthreads();
    int val = v;
    for (int off = 1; off < 256; off <<= 1) {
        const int y = (threadIdx.x >= off) ? sh[threadIdx.x - off] : 0;
        __syncthreads();
        val += y; sh[threadIdx.x] = val;
        __syncthreads();
    }
    if (i < N_NODES) base[i] = val - v;
    if (threadIdx.x == 255) bsum[blockIdx.x] = val;
}

__global__ __launch_bounds__(256) void scan2_k(int* __restrict__ bsum)
{
    __shared__ int sh[256];
    const int i = threadIdx.x;
    const int v = (i < NB_SCAN) ? bsum[i] : 0;
    sh[i] = v;
    __syncthreads();
    int val = v;
    for (int off = 1; off < 256; off <<= 1) {
        const int y = (i >= off) ? sh[i - off] : 0;
        __syncthreads();
        val += y; sh[i] = val;
        __syncthreads();
    }
    if (i < NB_SCAN) bsum[i] = val - v;
}

__global__ __launch_bounds__(256) void scatter_k(
    const int* __restrict__ src, const int* __restrict__ dst,
    const float* __restrict__ t, const int* __restrict__ base,
    const int* __restrict__ bsum, const int* __restrict__ rank,
    int2* __restrict__ edata)
{
    const int e = blockIdx.x * 256 + threadIdx.x;
    const int d = dst[e];
    const int pos = base[d] + bsum[d >> 8] + rank[e];
    edata[pos] = make_int2(src[e], __float_as_int(t[e]));
}

// ---------------------------------------------------------------------------
// Kernel B: gather attention, one wave / 4 nodes. MFMA te -> per-wave LDS tile
// (decouples MFMA C-layout from compute layout; wave-private => no barriers).
// Compute layout: lane l15 owns 8 consecutive dims of one edge; a kv row
// (256 B) is fetched by 16 lanes with ONE global_load_dwordx4 each (16 B).
// Lanes 0-7: k dims, lanes 8-15: v dims. Zero atomics.
// ---------------------------------------------------------------------------
__global__ __launch_bounds__(256) void gather_edge(
    const int2* __restrict__ edata, const int* __restrict__ base,
    const int* __restrict__ bsum, const int* __restrict__ cnt,
    const float* __restrict__ w_time, const float* __restrict__ b_time,
    const float* __restrict__ We_k, const float* __restrict__ We_v,
    const float* __restrict__ zq, const unsigned short* __restrict__ zkv,
    float* __restrict__ out)
{
    __shared__ float lds_all[4 * 16 * LSTR];   // 33792 B; per-wave private tiles
    const int tid  = threadIdx.x;
    const int w    = tid >> 6;
    const int lane = tid & 63;
    const int l15  = lane & 15;
    const int quad = lane >> 4;
    const int wid  = blockIdx.x * 4 + w;
    float* slds    = lds_all + w * 16 * LSTR;

    float wt[8], bt[8];
    #pragma unroll
    for (int j = 0; j < 8; ++j) {
        wt[j] = w_time[quad * 8 + j];
        bt[j] = b_time[quad * 8 + j];
    }
    bf16x8 bfrag[8];   // [We_k | We_v], B[k=quad*8+j][col=16*(g&3)+l15]
    #pragma unroll
    for (int g = 0; g < 8; ++g) {
        const float* W = (g < 4) ? We_k : We_v;
        const int col = 16 * (g & 3) + l15;
        #pragma unroll
        for (int j = 0; j < 8; ++j)
            bfrag[g][j] = f2bf(W[(quad * 8 + j) * OUT_DIM + col]);
    }

    for (int a = 0; a < 4; ++a) {
        const int n   = wid * 4 + a;
        const int b0  = base[n] + bsum[n >> 8];
        const int deg = cnt[n];

        // q in gather layout: lane (any quad) holds q dims [8*(l15&7), +8)
        const float4 qa = *(const float4*)(zq + (size_t)n * OUT_DIM + 8 * (l15 & 7));
        const float4 qb = *(const float4*)(zq + (size_t)n * OUT_DIM + 8 * (l15 & 7) + 4);

        float acc[8];
        #pragma unroll
        for (int j = 0; j < 8; ++j) acc[j] = 0.f;
        float lp = 0.f;

        for (int ch = 0; ch < deg; ch += 16) {
            const int e_l = b0 + ch + l15;                 // all quads: same 16 edges
            const int2 ed = edata[min(e_l, N_EDGES - 1)];
            const float tv = __int_as_float(ed.y);
            bf16x8 afrag;                                  // A[m=l15][k=quad*8+j]
            #pragma unroll
            for (int j = 0; j < 8; ++j)
                afrag[j] = f2bf(__cosf(tv * wt[j] + bt[j]));
            f32x4 c[8];
            #pragma unroll
            for (int g = 0; g < 8; ++g)
                c[g] = __builtin_amdgcn_mfma_f32_16x16x32_bf16(afrag, bfrag[g], (f32x4)0.0f, 0, 0, 0);
            // C -> per-wave LDS: row = quad*4+reg (edge-in-chunk), col = 16g+l15
            #pragma unroll
            for (int g = 0; g < 8; ++g)
                #pragma unroll
                for (int r = 0; r < 4; ++r)
                    slds[(quad * 4 + r) * LSTR + 16 * g + l15] = c[g][r];

            const int rem = deg - ch;
            #pragma unroll
            for (int r = 0; r < 4; ++r) {
                const int er   = quad * 4 + r;             // this quad's edge
                const int srcn = __shfl(ed.x, er, 64);
                const bool valid = (er < rem);
                // one 16B load: lane's 8 dims of the 256 B kv row
                const u16x8 kv8 = *(const u16x8*)(zkv + (size_t)srcn * 128 + 8 * l15);
                // ek/ev from LDS: cols [8*l15, +8) of row er (k cols 0-63, v 64-127)
                const float* lrow = slds + er * LSTR + 8 * l15;
                const float4 c0 = *(const float4*)lrow;
                const float4 c1 = *(const float4*)(lrow + 4);

                float p = qa.x * (bf2f(kv8[0]) + c0.x)
                        + qa.y * (bf2f(kv8[1]) + c0.y)
                        + qa.z * (bf2f(kv8[2]) + c0.z)
                        + qa.w * (bf2f(kv8[3]) + c0.w)
                        + qb.x * (bf2f(kv8[4]) + c1.x)
                        + qb.y * (bf2f(kv8[5]) + c1.y)
                        + qb.z * (bf2f(kv8[6]) + c1.z)
                        + qb.w * (bf2f(kv8[7]) + c1.w);
                // reduce over the head's 4 lanes (head0: l15 0-3, head1: 4-7)
                p += __shfl_xor(p, 1, 64);
                p += __shfl_xor(p, 2, 64);
                const float pe = valid ? __expf(p * 0.17677669529663687f) : 0.f;
                lp += pe;                                  // meaningful on lanes l15<8
                const float pv = __shfl_xor(pe, 8, 64);    // v-lanes get their head's pe
                acc[0] += pv * (bf2f(kv8[0]) + c0.x);      // v-lanes: v dims + ev
                acc[1] += pv * (bf2f(kv8[1]) + c0.y);
                acc[2] += pv * (bf2f(kv8[2]) + c0.z);
                acc[3] += pv * (bf2f(kv8[3]) + c0.w);
                acc[4] += pv * (bf2f(kv8[4]) + c1.x);
                acc[5] += pv * (bf2f(kv8[5]) + c1.y);
                acc[6] += pv * (bf2f(kv8[6]) + c1.z);
                acc[7] += pv * (bf2f(kv8[7]) + c1.w);
            }
        }

        // cross-quad reduction (same l15 across quads)
        #pragma unroll
        for (int off = 16; off < 64; off <<= 1) {
            #pragma unroll
            for (int j = 0; j < 8; ++j) acc[j] += __shfl_xor(acc[j], off, 64);
            lp += __shfl_xor(lp, off, 64);
        }
        const float ls  = __shfl_xor(lp, 8, 64);           // v-lanes: their head's sum
        if (quad == 0 && l15 >= 8) {
            const float inv = (ls > 0.f) ? 1.f / ls : 0.f;
            float* op = out + (size_t)n * OUT_DIM + 8 * (l15 - 8);
            float4 o0 = *(const float4*)op;
            float4 o1 = *(const float4*)(op + 4);
            o0.x += acc[0] * inv; o0.y += acc[1] * inv;
            o0.z += acc[2] * inv; o0.w += acc[3] * inv;
            o1.x += acc[4] * inv; o1.y += acc[5] * inv;
            o1.z += acc[6] * inv; o1.w += acc[7] * inv;
            *(float4*)op       = o0;
            *(float4*)(op + 4) = o1;
        }
    }
}

extern "C" void kernel_launch(void* const* d_in, const int* in_sizes, int n_in,
                              void* d_out, int out_size, void* d_ws, size_t ws_size,
                              hipStream_t stream) {
    (void)in_sizes; (void)n_in; (void)out_size; (void)ws_size;
    const int*   src    = (const int*)d_in[0];
    const int*   dst    = (const int*)d_in[1];
    const float* t      = (const float*)d_in[2];
    const float* x      = (const float*)d_in[3];
    const float* mem    = (const float*)d_in[4];
    const float* w_time = (const float*)d_in[5];
    const float* b_time = (const float*)d_in[6];
    const float* Wq     = (const float*)d_in[7];
    const float* Wk     = (const float*)d_in[8];
    const float* Wv     = (const float*)d_in[9];
    const float* We_k   = (const float*)d_in[10];
    const float* We_v   = (const float*)d_in[11];
    const float* Wskip  = (const float*)d_in[12];

    float*          ws   = (float*)d_ws;
    float*          zq   = ws;                                        // N*64 f32
    unsigned short* zkv  = (unsigned short*)(zq + (size_t)N_NODES * OUT_DIM); // N*128 bf16
    int* cnt  = (int*)(zkv + (size_t)N_NODES * 128);  // N  -- zeroed
    int* rank = cnt + N_NODES;                        // E
    int* base = rank + N_EDGES;                       // N
    int* bsum = base + N_NODES;                       // 256
    int2* edata = (int2*)(bsum + 256);                // E int2 (8B-aligned)
    float* out  = (float*)d_out;

    hipMemsetAsync(cnt, 0, (size_t)N_NODES * sizeof(int), stream);

    node_gemm<<<N_NODES / 16, 256, 0, stream>>>(x, mem, Wq, Wk, Wv, Wskip,
                                                dst, cnt, rank, zq, zkv, out);
    scan1_k  <<<NB_SCAN, 256, 0, stream>>>(cnt, base, bsum);
    scan2_k  <<<1, 256, 0, stream>>>(bsum);
    scatter_k<<<N_EDGES / 256, 256, 0, stream>>>(src, dst, t, base, bsum, rank, edata);
    gather_edge<<<N_NODES / 16, 256, 0, stream>>>(edata, base, bsum, cnt, w_time, b_time,
                                                  We_k, We_v, zq, zkv, out);
}